// Round 5
// baseline (168.183 us; speedup 1.0000x reference)
//
#include <hip/hip_runtime.h>
#include <cstdint>
#include <cstddef>

#define B 8
#define L 1024
#define DM 512
#define H 8
#define LN_EPS 1e-5f

// workspace layout (float offsets)
#define U_OFF    0        // DM*H = 4096         u[dm*8+h] = Wk[dm, h*64:] . wmap_k
#define CNT_OFF  4096     // 3 ints (phase counters) in the [4096,8192) gap
#define SK_OFF   8192     // H*B*L = 65536       sk[(h*B+b)*L + l]
#define PART_OFF 81920    // 8*H*B*DM = 262144   vbar partials [js][h][b][dm]
#define CTX_OFF  344064   // B*DM = 4096         ctxcat[b*DM + h*64+d]
#define OBP_OFF  348160   // 8*B*DM = 32768      obase partials [ms][b][n]

#define OUT_ELEMS ((size_t)B * L * DM)   // 4194304; attn matrix follows

typedef float f4 __attribute__((ext_vector_type(4)));

__device__ __forceinline__ float wave_sum(float s) {
#pragma unroll
    for (int off = 32; off > 0; off >>= 1) s += __shfl_xor(s, off, 64);
    return s;
}

// producer-consumer sync across blocks (agent scope: correct across XCDs)
__device__ __forceinline__ void wait_cnt(int* cnt, int target) {
    if (threadIdx.x == 0) {
        while (__hip_atomic_load(cnt, __ATOMIC_RELAXED, __HIP_MEMORY_SCOPE_AGENT) < target)
            __builtin_amdgcn_s_sleep(8);
    }
    __syncthreads();
    __builtin_amdgcn_fence(__ATOMIC_ACQUIRE, "agent");
}
__device__ __forceinline__ void signal_cnt(int* cnt) {
    __syncthreads();  // all block stores vmcnt-drained (in this XCD's L2)
    if (threadIdx.x == 0)
        __hip_atomic_fetch_add(cnt, 1, __ATOMIC_RELEASE, __HIP_MEMORY_SCOPE_AGENT);  // wbL2 + add
}

// ---------- A: u[dm*8+h] = Wk[dm, h*64:(h+1)*64] . wmap_k ; zero counters ----------
__global__ __launch_bounds__(64) void k_prep(const float* __restrict__ Wk,
                                             const float* __restrict__ Wmap,
                                             float* __restrict__ ws) {
    __shared__ float wm[64];
    int t = threadIdx.x;
    if (blockIdx.x == 0 && t < 3) ((int*)(ws + CNT_OFF))[t] = 0;
    wm[t] = Wmap[64 + t];
    __syncthreads();
    int h = t >> 3, part = t & 7;
#pragma unroll
    for (int i = 0; i < 8; ++i) {
        int dm = blockIdx.x * 8 + i;
        const float* row = Wk + (size_t)dm * (H * 64) + h * 64 + part * 8;
        float s = 0.f;
#pragma unroll
        for (int d = 0; d < 8; ++d) s += row[d] * wm[part * 8 + d];
        s += __shfl_xor(s, 1, 64);
        s += __shfl_xor(s, 2, 64);
        s += __shfl_xor(s, 4, 64);
        if (part == 0) ws[U_OFF + dm * H + h] = s;
    }
}

// ---------- B: sk[h,b,l] = k[b,l,:] . u[:,h] ----------
__global__ __launch_bounds__(256) void k_sk(const float* __restrict__ k,
                                            float* __restrict__ ws) {
    int wave = threadIdx.x >> 6, lane = threadIdx.x & 63;
    int row = blockIdx.x * 4 + wave;  // b*L + l
    int b = row >> 10, l = row & 1023;
    const float* krow = k + (size_t)row * DM;
    const float* u = ws + U_OFF;
    float acc[8] = {0, 0, 0, 0, 0, 0, 0, 0};
#pragma unroll
    for (int s8 = 0; s8 < 8; ++s8) {
        int dm = s8 * 64 + lane;
        float kv = krow[dm];
        const float4 ua = *(const float4*)(u + dm * 8);
        const float4 ub = *(const float4*)(u + dm * 8 + 4);
        acc[0] += kv * ua.x; acc[1] += kv * ua.y;
        acc[2] += kv * ua.z; acc[3] += kv * ua.w;
        acc[4] += kv * ub.x; acc[5] += kv * ub.y;
        acc[6] += kv * ub.z; acc[7] += kv * ub.w;
    }
#pragma unroll
    for (int off = 32; off > 0; off >>= 1) {
#pragma unroll
        for (int h = 0; h < 8; ++h) acc[h] += __shfl_xor(acc[h], off, 64);
    }
    float vout = 0.f;
#pragma unroll
    for (int h = 0; h < 8; ++h) if (lane == h) vout = acc[h];
    if (lane < 8)
        ws[SK_OFF + ((size_t)(lane * B + b)) * L + l] = vout;
}

// ---------- MEGA: roles by block range ----------
// [0,512)      vbar partials (fused softmax)      -> signal cnt[0]
// [512,576)    ctx  (wait cnt[0]==512)            -> signal cnt[1]
// [576,640)    obase partials (wait cnt[1]==64)   -> signal cnt[2]
// [640,4736)   attn: one 16-row broadcast task each, no sync (reads sk only)
// [4736,5248)  out = LN(q+obase), 16 rows each (wait cnt[2]==64); dispatched last
__global__ __launch_bounds__(256) void k_mega(
    const float* __restrict__ q, const float* __restrict__ v,
    const float* __restrict__ Wv, const float* __restrict__ bv,
    const float* __restrict__ Wfc, const float* __restrict__ bfc,
    const float* __restrict__ lns, const float* __restrict__ lnb,
    float* __restrict__ ws, float* __restrict__ out)
{
    __shared__ float smem[1032];
    int* cnt = (int*)(ws + CNT_OFF);
    int blk = blockIdx.x;
    int t = threadIdx.x, wave = t >> 6, lane = t & 63;

    if (blk < 512) {
        // ---- vbar: grid 512 = js<<6 | b<<3 | chunk; wave w -> h = 2w,2w+1
        int chunk = blk & 7, b = (blk >> 3) & 7, js = blk >> 6;
#pragma unroll
        for (int rep = 0; rep < 2; ++rep) {
            int h = wave * 2 + rep;
            const float* rowp = ws + SK_OFF + ((size_t)(h * B + b)) * L;
            const f4* r4 = (const f4*)(rowp + lane * 16);
            float part = 0.f;
#pragma unroll
            for (int i = 0; i < 4; ++i) {
                f4 x = r4[i];
                part += __expf(x.x) + __expf(x.y) + __expf(x.z) + __expf(x.w);
            }
            float s = wave_sum(part);
            float inv = 1.f / s;
            float2 seg = *(const float2*)(rowp + js * 128 + lane * 2);
            smem[h * 128 + lane * 2 + 0] = __expf(seg.x) * inv;
            smem[h * 128 + lane * 2 + 1] = __expf(seg.y) * inv;
        }
        __syncthreads();
        int dm = chunk * 64 + lane;
        const float* vb0 = v + ((size_t)b * L + js * 128) * DM + dm;
        int h0 = wave * 2;
        float a0 = 0.f, a1 = 0.f;
#pragma unroll 4
        for (int jj = 0; jj < 128; ++jj) {
            float vv = vb0[(size_t)jj * DM];
            a0 += smem[h0 * 128 + jj] * vv;
            a1 += smem[(h0 + 1) * 128 + jj] * vv;
        }
        ws[PART_OFF + ((size_t)((js * H + h0) * B + b)) * DM + dm] = a0;
        ws[PART_OFF + ((size_t)((js * H + h0 + 1) * B + b)) * DM + dm] = a1;
        signal_cnt(cnt + 0);
    } else if (blk < 576) {
        // ---- ctx: hb = blk-512; vb=[0,512), red=[512,768)
        wait_cnt(cnt + 0, 512);
        int hb = blk - 512;
        int h = hb >> 3, b = hb & 7;
#pragma unroll
        for (int it = 0; it < 2; ++it) {
            int dm = t + it * 256;
            float s = 0.f;
#pragma unroll
            for (int js = 0; js < 8; ++js)
                s += ws[PART_OFF + ((size_t)((js * H + h) * B + b)) * DM + dm];
            smem[dm] = s;
        }
        __syncthreads();
        float acc = 0.f;
#pragma unroll 4
        for (int i = 0; i < 128; ++i) {
            int dm = wave * 128 + i;
            acc += smem[dm] * Wv[(size_t)dm * DM + h * 64 + lane];
        }
        smem[512 + wave * 64 + lane] = acc;
        __syncthreads();
        if (wave == 0) {
            float r = smem[512 + lane] + smem[576 + lane] + smem[640 + lane]
                    + smem[704 + lane] + bv[h * 64 + lane];
            ws[CTX_OFF + (size_t)b * DM + h * 64 + lane] = r;
        }
        signal_cnt(cnt + 1);
    } else if (blk < 640) {
        // ---- obase partials: idx = blk-576 = ms<<3 | b
        wait_cnt(cnt + 1, 64);
        int idx = blk - 576;
        int b = idx & 7, ms = idx >> 3;
        if (t < 64) smem[t] = ws[CTX_OFF + (size_t)b * DM + ms * 64 + t];
        __syncthreads();
#pragma unroll
        for (int it = 0; it < 2; ++it) {
            int n = t + it * 256;
            float acc = 0.f;
#pragma unroll 4
            for (int m = 0; m < 64; ++m)
                acc += smem[m] * Wfc[(size_t)(ms * 64 + m) * DM + n];
            ws[OBP_OFF + (size_t)(ms * B + b) * DM + n] = acc;
        }
        signal_cnt(cnt + 2);
    } else if (blk < 4736) {
        // ---- attn: task = blk-640 = hb<<6 | ic ; softmax(sk row), 16-row NT broadcast
        int task = blk - 640;
        int hb = task >> 6, ic = task & 63;
        float4 s4 = *(const float4*)&ws[SK_OFF + (size_t)hb * L + t * 4];
        float e0 = __expf(s4.x), e1 = __expf(s4.y), e2 = __expf(s4.z), e3 = __expf(s4.w);
        float s = wave_sum(e0 + e1 + e2 + e3);
        if (lane == 0) smem[1024 + wave] = s;
        __syncthreads();
        float inv = 1.f / (smem[1024] + smem[1025] + smem[1026] + smem[1027]);
        f4 p4 = {e0 * inv, e1 * inv, e2 * inv, e3 * inv};
        float* base = out + OUT_ELEMS + ((size_t)hb * L + (size_t)ic * 16) * L + t * 4;
#pragma unroll
        for (int r = 0; r < 16; ++r)
            __builtin_nontemporal_store(p4, (f4*)(base + (size_t)r * L));
    } else {
        // ---- out: rblk = blk-4736; rows rblk*16..+16; obf=[0,512)
        wait_cnt(cnt + 2, 64);
        int rblk = blk - 4736;
        int b = rblk >> 6;
        for (int i = t; i < DM; i += 256) {
            float s = bfc[i];
#pragma unroll
            for (int ms = 0; ms < 8; ++ms)
                s += ws[OBP_OFF + (size_t)(ms * B + b) * DM + i];
            smem[i] = s;
        }
        __syncthreads();
#pragma unroll
        for (int rep = 0; rep < 4; ++rep) {
            int row = rblk * 16 + rep * 4 + wave;
            const float* qr = q + (size_t)row * DM;
            int d0 = lane * 8;
            float4 a = *(const float4*)(qr + d0);
            float4 c = *(const float4*)(qr + d0 + 4);
            float x[8] = {a.x + smem[d0],     a.y + smem[d0 + 1],
                          a.z + smem[d0 + 2], a.w + smem[d0 + 3],
                          c.x + smem[d0 + 4], c.y + smem[d0 + 5],
                          c.z + smem[d0 + 6], c.w + smem[d0 + 7]};
            float sum = 0.f, sq = 0.f;
#pragma unroll
            for (int i = 0; i < 8; ++i) { sum += x[i]; sq += x[i] * x[i]; }
#pragma unroll
            for (int off = 32; off > 0; off >>= 1) {
                sum += __shfl_xor(sum, off, 64);
                sq  += __shfl_xor(sq,  off, 64);
            }
            float mu = sum * (1.f / DM);
            float var = sq * (1.f / DM) - mu * mu;
            float invs = rsqrtf(var + LN_EPS);
            float4 sa = *(const float4*)(lns + d0);
            float4 sc = *(const float4*)(lns + d0 + 4);
            float4 ba = *(const float4*)(lnb + d0);
            float4 bb = *(const float4*)(lnb + d0 + 4);
            float sarr[8] = {sa.x, sa.y, sa.z, sa.w, sc.x, sc.y, sc.z, sc.w};
            float barr[8] = {ba.x, ba.y, ba.z, ba.w, bb.x, bb.y, bb.z, bb.w};
            float y[8];
#pragma unroll
            for (int i = 0; i < 8; ++i) y[i] = (x[i] - mu) * invs * sarr[i] + barr[i];
            float4 o0 = {y[0], y[1], y[2], y[3]};
            float4 o1 = {y[4], y[5], y[6], y[7]};
            *(float4*)(out + (size_t)row * DM + d0) = o0;
            *(float4*)(out + (size_t)row * DM + d0 + 4) = o1;
        }
    }
}

extern "C" void kernel_launch(void* const* d_in, const int* in_sizes, int n_in,
                              void* d_out, int out_size, void* d_ws, size_t ws_size,
                              hipStream_t stream) {
    const float* q    = (const float*)d_in[0];
    const float* k    = (const float*)d_in[1];
    const float* v    = (const float*)d_in[2];
    // d_in[3]=Wq, d_in[4]=bq, d_in[6]=bk, d_in[9][:64], d_in[10]=bmap all cancel in softmax
    const float* Wk   = (const float*)d_in[5];
    const float* Wv   = (const float*)d_in[7];
    const float* bv   = (const float*)d_in[8];
    const float* Wmap = (const float*)d_in[9];
    const float* Wfc  = (const float*)d_in[11];
    const float* bfc  = (const float*)d_in[12];
    const float* lns  = (const float*)d_in[13];
    const float* lnb  = (const float*)d_in[14];
    float* out = (float*)d_out;
    float* ws  = (float*)d_ws;

    hipLaunchKernelGGL(k_prep, dim3(64),   dim3(64),  0, stream, Wk, Wmap, ws);
    hipLaunchKernelGGL(k_sk,   dim3(2048), dim3(256), 0, stream, k, ws);
    hipLaunchKernelGGL(k_mega, dim3(5248), dim3(256), 0, stream,
                       q, v, Wv, bv, Wfc, bfc, lns, lnb, ws, out);
}

// Round 6
// 149.367 us; speedup vs baseline: 1.1260x; 1.1260x over previous
//
#include <hip/hip_runtime.h>
#include <cstdint>
#include <cstddef>

#define B 8
#define L 1024
#define DM 512
#define H 8
#define LN_EPS 1e-5f

// workspace layout (float offsets)
#define U_OFF    0        // DM*H = 4096         u[dm*8+h] = Wk[dm, h*64:] . wmap_k
#define SK_OFF   8192     // H*B*L = 65536       sk[(h*B+b)*L + l]
#define PART_OFF 81920    // 8*H*B*DM = 262144   vbar partials [js][h][b][dm]
#define OB_OFF   344064   // B*DM = 4096         obase[b*DM + n] (incl. bfc)

#define OUT_ELEMS ((size_t)B * L * DM)   // 4194304; attn matrix follows

typedef float f4 __attribute__((ext_vector_type(4)));

__device__ __forceinline__ float wave_sum(float s) {
#pragma unroll
    for (int off = 32; off > 0; off >>= 1) s += __shfl_xor(s, off, 64);
    return s;
}

// attn task: softmax(sk row hb) (no max-sub: |sk| small), NT-broadcast to 16 rows.
// red = 4-float shared scratch.
__device__ __forceinline__ void attn_task(int task, const float* __restrict__ ws,
                                          float* __restrict__ out, float* red) {
    int hb = task >> 6, ic = task & 63;
    int t = threadIdx.x, wave = t >> 6, lane = t & 63;
    float4 s4 = *(const float4*)&ws[SK_OFF + (size_t)hb * L + t * 4];
    float e0 = __expf(s4.x), e1 = __expf(s4.y), e2 = __expf(s4.z), e3 = __expf(s4.w);
    float s = wave_sum(e0 + e1 + e2 + e3);
    if (lane == 0) red[wave] = s;
    __syncthreads();
    float inv = 1.f / (red[0] + red[1] + red[2] + red[3]);
    f4 p4 = {e0 * inv, e1 * inv, e2 * inv, e3 * inv};
    float* base = out + OUT_ELEMS + ((size_t)hb * L + (size_t)ic * 16) * L + t * 4;
#pragma unroll
    for (int r = 0; r < 16; ++r)
        __builtin_nontemporal_store(p4, (f4*)(base + (size_t)r * L));
}

// ---------- L1: u[dm*8+h] = Wk[dm, h*64:(h+1)*64] . wmap_k ----------
__global__ __launch_bounds__(64) void k_prep(const float* __restrict__ Wk,
                                             const float* __restrict__ Wmap,
                                             float* __restrict__ ws) {
    __shared__ float wm[64];
    int t = threadIdx.x;
    wm[t] = Wmap[64 + t];
    __syncthreads();
    int h = t >> 3, part = t & 7;
#pragma unroll
    for (int i = 0; i < 8; ++i) {
        int dm = blockIdx.x * 8 + i;
        const float* row = Wk + (size_t)dm * (H * 64) + h * 64 + part * 8;
        float s = 0.f;
#pragma unroll
        for (int d = 0; d < 8; ++d) s += row[d] * wm[part * 8 + d];
        s += __shfl_xor(s, 1, 64);
        s += __shfl_xor(s, 2, 64);
        s += __shfl_xor(s, 4, 64);
        if (part == 0) ws[U_OFF + dm * H + h] = s;
    }
}

// ---------- L2: sk[h,b,l] = k[b,l,:] . u[:,h] ----------
__global__ __launch_bounds__(256) void k_sk(const float* __restrict__ k,
                                            float* __restrict__ ws) {
    int wave = threadIdx.x >> 6, lane = threadIdx.x & 63;
    int row = blockIdx.x * 4 + wave;  // b*L + l
    int b = row >> 10, l = row & 1023;
    const float* krow = k + (size_t)row * DM;
    const float* u = ws + U_OFF;
    float acc[8] = {0, 0, 0, 0, 0, 0, 0, 0};
#pragma unroll
    for (int s8 = 0; s8 < 8; ++s8) {
        int dm = s8 * 64 + lane;
        float kv = krow[dm];
        const float4 ua = *(const float4*)(u + dm * 8);
        const float4 ub = *(const float4*)(u + dm * 8 + 4);
        acc[0] += kv * ua.x; acc[1] += kv * ua.y;
        acc[2] += kv * ua.z; acc[3] += kv * ua.w;
        acc[4] += kv * ub.x; acc[5] += kv * ub.y;
        acc[6] += kv * ub.z; acc[7] += kv * ub.w;
    }
#pragma unroll
    for (int off = 32; off > 0; off >>= 1) {
#pragma unroll
        for (int h = 0; h < 8; ++h) acc[h] += __shfl_xor(acc[h], off, 64);
    }
    float vout = 0.f;
#pragma unroll
    for (int h = 0; h < 8; ++h) if (lane == h) vout = acc[h];
    if (lane < 8)
        ws[SK_OFF + ((size_t)(lane * B + b)) * L + l] = vout;
}

// ---------- L3: vbar partials [0,512)  ||  attn tasks [0,1408) ----------
__global__ __launch_bounds__(256) void k_l3(const float* __restrict__ v,
                                            float* __restrict__ ws,
                                            float* __restrict__ out) {
    __shared__ float smem[1028];   // vbar: ps[8][128]; attn: red at [1024,1028)
    int blk = blockIdx.x;
    int t = threadIdx.x, wave = t >> 6, lane = t & 63;
    if (blk < 512) {
        // vbar: blk = js<<6 | b<<3 | chunk; wave w -> h = 2w, 2w+1
        int chunk = blk & 7, b = (blk >> 3) & 7, js = blk >> 6;
#pragma unroll
        for (int rep = 0; rep < 2; ++rep) {
            int h = wave * 2 + rep;
            const float* rowp = ws + SK_OFF + ((size_t)(h * B + b)) * L;
            const f4* r4 = (const f4*)(rowp + lane * 16);
            float part = 0.f;
#pragma unroll
            for (int i = 0; i < 4; ++i) {
                f4 x = r4[i];
                part += __expf(x.x) + __expf(x.y) + __expf(x.z) + __expf(x.w);
            }
            float s = wave_sum(part);
            float inv = 1.f / s;
            float2 seg = *(const float2*)(rowp + js * 128 + lane * 2);
            smem[h * 128 + lane * 2 + 0] = __expf(seg.x) * inv;
            smem[h * 128 + lane * 2 + 1] = __expf(seg.y) * inv;
        }
        __syncthreads();
        int dm = chunk * 64 + lane;
        const float* vb0 = v + ((size_t)b * L + js * 128) * DM + dm;
        int h0 = wave * 2;
        float a0 = 0.f, a1 = 0.f;
#pragma unroll 4
        for (int jj = 0; jj < 128; ++jj) {
            float vv = vb0[(size_t)jj * DM];
            a0 += smem[h0 * 128 + jj] * vv;
            a1 += smem[(h0 + 1) * 128 + jj] * vv;
        }
        ws[PART_OFF + ((size_t)((js * H + h0) * B + b)) * DM + dm] = a0;
        ws[PART_OFF + ((size_t)((js * H + h0 + 1) * B + b)) * DM + dm] = a1;
    } else {
        attn_task(blk - 512, ws, out, smem + 1024);
    }
}

// ---------- L4: ctx+obase merged [0,64)  ||  attn tasks [1408,2816) ----------
// block idx<64: b = idx>>3, ns = idx&7 -> obase[b, ns*64 .. ns*64+64)
__global__ __launch_bounds__(256) void k_l4(const float* __restrict__ Wv,
                                            const float* __restrict__ bv,
                                            const float* __restrict__ Wfc,
                                            const float* __restrict__ bfc,
                                            float* __restrict__ ws,
                                            float* __restrict__ out) {
    __shared__ float vbs[4096];        // vbar sums [h][dm] 16 KB
    __shared__ float ctxs[512];
    __shared__ float red[4][64];
    int blk = blockIdx.x;
    int t = threadIdx.x;
    if (blk < 64) {
        int b = blk >> 3, ns = blk & 7;
        for (int i = t; i < 4096; i += 256) {
            int h = i >> 9, dm = i & 511;
            float s = 0.f;
#pragma unroll
            for (int js = 0; js < 8; ++js)
                s += ws[PART_OFF + ((size_t)((js * H + h) * B + b)) * DM + dm];
            vbs[i] = s;
        }
        __syncthreads();
        // ctx[b,m] = vbs[m>>6][:] . Wv[:,m] + bv[m], m = t, t+256
#pragma unroll
        for (int mo = 0; mo < 2; ++mo) {
            int m = t + mo * 256;
            const float* vh = &vbs[(m >> 6) << 9];
            float acc = bv[m];
#pragma unroll 4
            for (int dm = 0; dm < DM; ++dm)
                acc += vh[dm] * Wv[(size_t)dm * DM + m];
            ctxs[m] = acc;
        }
        __syncthreads();
        // obase[b, ns*64+nl] = ctx . Wfc[:, n] + bfc[n]
        int seg = t >> 6, nl = t & 63;
        int n = ns * 64 + nl;
        float acc = 0.f;
#pragma unroll 4
        for (int i = 0; i < 128; ++i) {
            int m = seg * 128 + i;
            acc += ctxs[m] * Wfc[(size_t)m * DM + n];
        }
        red[seg][nl] = acc;
        __syncthreads();
        if (seg == 0) {
            float r = red[0][nl] + red[1][nl] + red[2][nl] + red[3][nl] + bfc[n];
            ws[OB_OFF + (size_t)b * DM + n] = r;
        }
    } else {
        attn_task(1408 + (blk - 64), ws, out, &red[0][0]);
    }
}

// ---------- L5: out = LN(q+obase) [0,512)  ||  attn tasks [2816,4096) ----------
__global__ __launch_bounds__(256) void k_l5(const float* __restrict__ q,
                                            const float* __restrict__ lns,
                                            const float* __restrict__ lnb,
                                            float* __restrict__ ws,
                                            float* __restrict__ out) {
    __shared__ float obf[516];   // [0,512) obase; [512,516) attn red
    int blk = blockIdx.x;
    int t = threadIdx.x, wave = t >> 6, lane = t & 63;
    if (blk < 512) {
        int b = blk >> 6;
        for (int i = t; i < DM; i += 256)
            obf[i] = ws[OB_OFF + (size_t)b * DM + i];
        __syncthreads();
#pragma unroll
        for (int rep = 0; rep < 4; ++rep) {
            int row = blk * 16 + rep * 4 + wave;
            const float* qr = q + (size_t)row * DM;
            int d0 = lane * 8;
            float4 a = *(const float4*)(qr + d0);
            float4 c = *(const float4*)(qr + d0 + 4);
            float x[8] = {a.x + obf[d0],     a.y + obf[d0 + 1],
                          a.z + obf[d0 + 2], a.w + obf[d0 + 3],
                          c.x + obf[d0 + 4], c.y + obf[d0 + 5],
                          c.z + obf[d0 + 6], c.w + obf[d0 + 7]};
            float sum = 0.f, sq = 0.f;
#pragma unroll
            for (int i = 0; i < 8; ++i) { sum += x[i]; sq += x[i] * x[i]; }
#pragma unroll
            for (int off = 32; off > 0; off >>= 1) {
                sum += __shfl_xor(sum, off, 64);
                sq  += __shfl_xor(sq,  off, 64);
            }
            float mu = sum * (1.f / DM);
            float var = sq * (1.f / DM) - mu * mu;
            float invs = rsqrtf(var + LN_EPS);
            float4 sa = *(const float4*)(lns + d0);
            float4 sc = *(const float4*)(lns + d0 + 4);
            float4 ba = *(const float4*)(lnb + d0);
            float4 bb = *(const float4*)(lnb + d0 + 4);
            float sarr[8] = {sa.x, sa.y, sa.z, sa.w, sc.x, sc.y, sc.z, sc.w};
            float barr[8] = {ba.x, ba.y, ba.z, ba.w, bb.x, bb.y, bb.z, bb.w};
            float y[8];
#pragma unroll
            for (int i = 0; i < 8; ++i) y[i] = (x[i] - mu) * invs * sarr[i] + barr[i];
            float4 o0 = {y[0], y[1], y[2], y[3]};
            float4 o1 = {y[4], y[5], y[6], y[7]};
            *(float4*)(out + (size_t)row * DM + d0) = o0;
            *(float4*)(out + (size_t)row * DM + d0 + 4) = o1;
        }
    } else {
        attn_task(2816 + (blk - 512), ws, out, obf + 512);
    }
}

extern "C" void kernel_launch(void* const* d_in, const int* in_sizes, int n_in,
                              void* d_out, int out_size, void* d_ws, size_t ws_size,
                              hipStream_t stream) {
    const float* q    = (const float*)d_in[0];
    const float* k    = (const float*)d_in[1];
    const float* v    = (const float*)d_in[2];
    // d_in[3]=Wq, d_in[4]=bq, d_in[6]=bk, d_in[9][:64], d_in[10]=bmap all cancel in softmax
    const float* Wk   = (const float*)d_in[5];
    const float* Wv   = (const float*)d_in[7];
    const float* bv   = (const float*)d_in[8];
    const float* Wmap = (const float*)d_in[9];
    const float* Wfc  = (const float*)d_in[11];
    const float* bfc  = (const float*)d_in[12];
    const float* lns  = (const float*)d_in[13];
    const float* lnb  = (const float*)d_in[14];
    float* out = (float*)d_out;
    float* ws  = (float*)d_ws;

    hipLaunchKernelGGL(k_prep, dim3(64),   dim3(64),  0, stream, Wk, Wmap, ws);
    hipLaunchKernelGGL(k_sk,   dim3(2048), dim3(256), 0, stream, k, ws);
    hipLaunchKernelGGL(k_l3,   dim3(1920), dim3(256), 0, stream, v, ws, out);
    hipLaunchKernelGGL(k_l4,   dim3(1472), dim3(256), 0, stream, Wv, bv, Wfc, bfc, ws, out);
    hipLaunchKernelGGL(k_l5,   dim3(1792), dim3(256), 0, stream, q, lns, lnb, ws, out);
}